// Round 5
// baseline (351.801 us; speedup 1.0000x reference)
//
#include <hip/hip_runtime.h>

// Problem constants (fixed by setup_inputs):
//   T=16384 tokens, H=3072 hidden, E=64 experts, capacity=256
//   dispatch size = E*cap = 16384 (multiple of 256 already)
#define T_TOKENS 16384
#define HIDDEN   3072
#define NEXP     64
#define CAP      256
#define BLK      256
#define NGB      (T_TOKENS / BLK)      // 64 gating blocks (256 tokens each)
#define DSIZE    (NEXP * CAP)          // 16384 dispatch rows
#define NW       (BLK / 64)            // 4 waves per block

// ---------------------------------------------------------------------------
// K1: per-token gating. One thread = one token. Wave-parallel ordered rank:
// match-any via 6 ballots over the expert-id bits, then cross-wave prefix via
// per-wave LDS counts. Writes per-token (expert, rank, score) and the
// per-block expert histogram.
// ---------------------------------------------------------------------------
__global__ __launch_bounds__(BLK) void gate_kernel(
    const float* __restrict__ logits,
    int* __restrict__ expertOut, int* __restrict__ rankOut,
    float* __restrict__ scoreOut, int* __restrict__ histOut) {
  __shared__ int wcnt[NW][NEXP];   // per-wave expert counts

  const int tid  = (int)threadIdx.x;
  const int lane = tid & 63;
  const int w    = tid >> 6;
  const int t    = blockIdx.x * BLK + tid;

  // 64 logits per token, contiguous 256 B -> float4 loads.
  const float4* lg = (const float4*)(logits + (size_t)t * NEXP);
  float l[NEXP];
#pragma unroll
  for (int i = 0; i < NEXP / 4; ++i) {
    float4 v = lg[i];
    l[4 * i + 0] = v.x; l[4 * i + 1] = v.y;
    l[4 * i + 2] = v.z; l[4 * i + 3] = v.w;
  }

  // First-occurrence argmax (matches jnp.argmax) + softmax prob at argmax.
  float mx = l[0];
  int arg = 0;
#pragma unroll
  for (int i = 1; i < NEXP; ++i)
    if (l[i] > mx) { mx = l[i]; arg = i; }
  float s = 0.f;
#pragma unroll
  for (int i = 0; i < NEXP; ++i) s += __expf(l[i] - mx);
  const float score = 1.0f / s;

  ((int*)wcnt)[tid] = 0;           // NW*NEXP == BLK: one entry per thread
  __syncthreads();

  // match-any: mask of lanes in my wave with the same expert (6 ballots).
  unsigned long long m = ~0ull;
#pragma unroll
  for (int b = 0; b < 6; ++b) {
    unsigned long long bal = __ballot((arg >> b) & 1);
    m &= ((arg >> b) & 1) ? bal : ~bal;
  }
  const unsigned long long ltm = (1ull << lane) - 1ull;  // lanes below me
  const int rankInWave = __popcll(m & ltm);
  const bool leader = (__ffsll((unsigned long long)m) - 1) == lane;
  if (leader) wcnt[w][arg] = __popcll(m);
  __syncthreads();

  int r = rankInWave;
#pragma unroll
  for (int w2 = 0; w2 < NW; ++w2)
    if (w2 < w) r += wcnt[w2][arg];

  expertOut[t] = arg;
  rankOut[t]   = r;
  scoreOut[t]  = score;
  if (tid < NEXP) {
    int h = 0;
#pragma unroll
    for (int w2 = 0; w2 < NW; ++w2) h += wcnt[w2][tid];
    histOut[blockIdx.x * NEXP + tid] = h;
  }
}

// ---------------------------------------------------------------------------
// K2: finalize. Each of the 64 blocks redundantly loads the 64x64 histogram
// (16 KB) into LDS and computes its own per-expert base prefix -- no
// cross-block sync needed. Then one thread per token: metadata outputs +
// slot->token source map for the scatter kernel.
// ---------------------------------------------------------------------------
__global__ __launch_bounds__(BLK) void finalize_kernel(
    const int* __restrict__ hist, const int* __restrict__ expert,
    const int* __restrict__ rank, const float* __restrict__ score,
    int* __restrict__ srcmap, float* __restrict__ sscore,
    int* __restrict__ kcnt,
    float* __restrict__ scoreOut, float* __restrict__ assignOut,
    float* __restrict__ slotsOut, float* __restrict__ countsOut) {
  __shared__ int h[NGB * NEXP];    // 16 KB
  __shared__ int baseSh[NEXP];

  const int tid = (int)threadIdx.x;
  const int b   = (int)blockIdx.x;

  for (int i = tid; i < NGB * NEXP; i += BLK) h[i] = hist[i];
  __syncthreads();

  if (tid < NEXP) {
    int base = 0, tot = 0;
    for (int b2 = 0; b2 < NGB; ++b2) {
      int c = h[b2 * NEXP + tid];
      if (b2 < b) base += c;
      tot += c;
    }
    baseSh[tid] = base;
    if (b == 0) {
      int kc = min(tot, CAP);
      kcnt[tid] = kc;
      countsOut[tid] = (float)kc;
    }
  }
  __syncthreads();

  const int t   = b * BLK + tid;
  const int e   = expert[t];
  const int loc = baseSh[e] + rank[t];
  const float s = score[t];
  const bool keep = loc < CAP;

  scoreOut[t]  = keep ? s : 0.0f;
  assignOut[t] = (float)e;
  slotsOut[t]  = keep ? (float)(e * CAP + loc) : -1.0f;
  if (keep) {
    const int slot = e * CAP + loc;
    srcmap[slot] = t;
    sscore[slot] = s;
  }
}

// ---------------------------------------------------------------------------
// K3: one block per dispatch row. Uniform per-block branch: copy scaled
// activation row (slot is filled) or write zeros (slot unfilled).
// ---------------------------------------------------------------------------
__global__ __launch_bounds__(BLK) void scatter_kernel(
    const float* __restrict__ act, const int* __restrict__ srcmap,
    const float* __restrict__ sscore, const int* __restrict__ kcnt,
    float* __restrict__ moe) {
  const int i   = (int)blockIdx.x;
  const int e   = i >> 8;          // i / CAP
  const int pos = i & (CAP - 1);

  float4* dst = (float4*)(moe + (size_t)i * HIDDEN);
  if (pos < kcnt[e]) {
    const int t   = srcmap[i];
    const float s = sscore[i];
    const float4* src = (const float4*)(act + (size_t)t * HIDDEN);
#pragma unroll
    for (int k = threadIdx.x; k < HIDDEN / 4; k += BLK) {
      float4 v = src[k];
      v.x *= s; v.y *= s; v.z *= s; v.w *= s;
      dst[k] = v;
    }
  } else {
    const float4 z = make_float4(0.f, 0.f, 0.f, 0.f);
#pragma unroll
    for (int k = threadIdx.x; k < HIDDEN / 4; k += BLK) dst[k] = z;
  }
}

// ---------------------------------------------------------------------------
extern "C" void kernel_launch(void* const* d_in, const int* in_sizes, int n_in,
                              void* d_out, int out_size, void* d_ws, size_t ws_size,
                              hipStream_t stream) {
  const float* act    = (const float*)d_in[0];
  const float* logits = (const float*)d_in[1];
  // d_in[2] is capacity==256, fixed; baked in as CAP.

  float* out       = (float*)d_out;
  float* moe       = out;                                  // [DSIZE*HIDDEN]
  float* scoreOut  = out + (size_t)DSIZE * HIDDEN;         // [T]
  float* assignOut = scoreOut + T_TOKENS;                  // [T] (int as float)
  float* slotsOut  = assignOut + T_TOKENS;                 // [T] (int as float)
  float* countsOut = slotsOut + T_TOKENS;                  // [E] (int as float)

  int*   expert = (int*)d_ws;                              // [T]
  int*   rank   = expert + T_TOKENS;                       // [T]
  float* score  = (float*)(rank + T_TOKENS);               // [T]
  int*   hist   = (int*)(score + T_TOKENS);                // [NGB*NEXP]
  int*   kcnt   = hist + NGB * NEXP;                       // [NEXP]
  int*   srcmap = kcnt + NEXP;                             // [DSIZE]
  float* sscore = (float*)(srcmap + DSIZE);                // [DSIZE]

  gate_kernel<<<NGB, BLK, 0, stream>>>(logits, expert, rank, score, hist);
  finalize_kernel<<<NGB, BLK, 0, stream>>>(hist, expert, rank, score,
                                           srcmap, sscore, kcnt,
                                           scoreOut, assignOut, slotsOut,
                                           countsOut);
  scatter_kernel<<<DSIZE, BLK, 0, stream>>>(act, srcmap, sscore, kcnt, moe);
}

// Round 6
// 341.242 us; speedup vs baseline: 1.0309x; 1.0309x over previous
//
#include <hip/hip_runtime.h>

// Problem constants (fixed by setup_inputs):
//   T=16384 tokens, H=3072 hidden, E=64 experts, capacity=256
//   dispatch size = E*cap = 16384 (multiple of 256 already)
#define T_TOKENS 16384
#define HIDDEN   3072
#define NEXP     64
#define CAP      256
#define BLK      256
#define NGB      (T_TOKENS / BLK)      // 64 gating blocks (256 tokens each)
#define DSIZE    (NEXP * CAP)          // 16384 dispatch rows
#define NW       (BLK / 64)            // 4 waves per block
#define RPB      8                     // scatter rows per block

typedef float f4 __attribute__((ext_vector_type(4)));

// ---------------------------------------------------------------------------
// K1: per-token gating. One thread = one token. Ballot-based ordered rank.
// Also initializes srcmap[t] = -1 (t spans DSIZE == T_TOKENS) so the scatter
// kernel can test "filled" with a single srcmap load, independent of ws
// poison state.
// ---------------------------------------------------------------------------
__global__ __launch_bounds__(BLK) void gate_kernel(
    const float* __restrict__ logits,
    int* __restrict__ expertOut, int* __restrict__ rankOut,
    float* __restrict__ scoreOut, int* __restrict__ histOut,
    int* __restrict__ srcmap) {
  __shared__ int wcnt[NW][NEXP];   // per-wave expert counts

  const int tid  = (int)threadIdx.x;
  const int lane = tid & 63;
  const int w    = tid >> 6;
  const int t    = blockIdx.x * BLK + tid;

  srcmap[t] = -1;                  // slot-indexed init (T_TOKENS == DSIZE)

  // 64 logits per token, contiguous 256 B -> float4 loads.
  const f4* lg = (const f4*)(logits + (size_t)t * NEXP);
  float l[NEXP];
#pragma unroll
  for (int i = 0; i < NEXP / 4; ++i) {
    f4 v = lg[i];
    l[4 * i + 0] = v.x; l[4 * i + 1] = v.y;
    l[4 * i + 2] = v.z; l[4 * i + 3] = v.w;
  }

  // First-occurrence argmax (matches jnp.argmax) + softmax prob at argmax.
  float mx = l[0];
  int arg = 0;
#pragma unroll
  for (int i = 1; i < NEXP; ++i)
    if (l[i] > mx) { mx = l[i]; arg = i; }
  float s = 0.f;
#pragma unroll
  for (int i = 0; i < NEXP; ++i) s += __expf(l[i] - mx);
  const float score = 1.0f / s;

  ((int*)wcnt)[tid] = 0;           // NW*NEXP == BLK: one entry per thread
  __syncthreads();

  // match-any: mask of lanes in my wave with the same expert (6 ballots).
  unsigned long long m = ~0ull;
#pragma unroll
  for (int b = 0; b < 6; ++b) {
    unsigned long long bal = __ballot((arg >> b) & 1);
    m &= ((arg >> b) & 1) ? bal : ~bal;
  }
  const unsigned long long ltm = (1ull << lane) - 1ull;  // lanes below me
  const int rankInWave = __popcll(m & ltm);
  const bool leader = (__ffsll((unsigned long long)m) - 1) == lane;
  if (leader) wcnt[w][arg] = __popcll(m);
  __syncthreads();

  int r = rankInWave;
#pragma unroll
  for (int w2 = 0; w2 < NW; ++w2)
    if (w2 < w) r += wcnt[w2][arg];

  expertOut[t] = arg;
  rankOut[t]   = r;
  scoreOut[t]  = score;
  if (tid < NEXP) {
    int h = 0;
#pragma unroll
    for (int w2 = 0; w2 < NW; ++w2) h += wcnt[w2][tid];
    histOut[blockIdx.x * NEXP + tid] = h;
  }
}

// ---------------------------------------------------------------------------
// K2: finalize. Each of the 64 blocks redundantly loads the 64x64 histogram
// (16 KB) into LDS and computes its own per-expert base prefix -- no
// cross-block sync needed. Then one thread per token: metadata outputs +
// slot->token source map (filled slots only; unfilled stay -1 from K1).
// ---------------------------------------------------------------------------
__global__ __launch_bounds__(BLK) void finalize_kernel(
    const int* __restrict__ hist, const int* __restrict__ expert,
    const int* __restrict__ rank, const float* __restrict__ score,
    int* __restrict__ srcmap, float* __restrict__ sscore,
    float* __restrict__ scoreOut, float* __restrict__ assignOut,
    float* __restrict__ slotsOut, float* __restrict__ countsOut) {
  __shared__ int h[NGB * NEXP];    // 16 KB
  __shared__ int baseSh[NEXP];

  const int tid = (int)threadIdx.x;
  const int b   = (int)blockIdx.x;

  for (int i = tid; i < NGB * NEXP; i += BLK) h[i] = hist[i];
  __syncthreads();

  if (tid < NEXP) {
    int base = 0, tot = 0;
    for (int b2 = 0; b2 < NGB; ++b2) {
      int c = h[b2 * NEXP + tid];
      if (b2 < b) base += c;
      tot += c;
    }
    baseSh[tid] = base;
    if (b == 0) countsOut[tid] = (float)min(tot, CAP);
  }
  __syncthreads();

  const int t   = b * BLK + tid;
  const int e   = expert[t];
  const int loc = baseSh[e] + rank[t];
  const float s = score[t];
  const bool keep = loc < CAP;

  scoreOut[t]  = keep ? s : 0.0f;
  assignOut[t] = (float)e;
  slotsOut[t]  = keep ? (float)(e * CAP + loc) : -1.0f;
  if (keep) {
    const int slot = e * CAP + loc;
    srcmap[slot] = t;
    sscore[slot] = s;
  }
}

// ---------------------------------------------------------------------------
// K3: scatter. 2048 blocks x 8 rows each. All 8 srcmap entries preloaded
// (independent uniform loads -> hoisted scalar loads, latency overlapped).
// Streaming copy with non-temporal loads/stores (no reuse of act or moe).
// ---------------------------------------------------------------------------
__global__ __launch_bounds__(BLK) void scatter_kernel(
    const float* __restrict__ act, const int* __restrict__ srcmap,
    const float* __restrict__ sscore, float* __restrict__ moe) {
  const int tid  = (int)threadIdx.x;
  const int base = (int)blockIdx.x * RPB;

  int src[RPB];
#pragma unroll
  for (int r = 0; r < RPB; ++r) src[r] = srcmap[base + r];

#pragma unroll
  for (int r = 0; r < RPB; ++r) {
    const int row = base + r;
    f4* dst = (f4*)(moe + (size_t)row * HIDDEN);
    if (src[r] >= 0) {
      const float s = sscore[row];
      const f4* sp = (const f4*)(act + (size_t)src[r] * HIDDEN);
#pragma unroll
      for (int k = 0; k < HIDDEN / 4 / BLK; ++k) {        // 3 iterations
        f4 v = __builtin_nontemporal_load(&sp[tid + k * BLK]);
        v *= s;
        __builtin_nontemporal_store(v, &dst[tid + k * BLK]);
      }
    } else {
      const f4 z = {0.f, 0.f, 0.f, 0.f};
#pragma unroll
      for (int k = 0; k < HIDDEN / 4 / BLK; ++k)
        __builtin_nontemporal_store(z, &dst[tid + k * BLK]);
    }
  }
}

// ---------------------------------------------------------------------------
extern "C" void kernel_launch(void* const* d_in, const int* in_sizes, int n_in,
                              void* d_out, int out_size, void* d_ws, size_t ws_size,
                              hipStream_t stream) {
  const float* act    = (const float*)d_in[0];
  const float* logits = (const float*)d_in[1];
  // d_in[2] is capacity==256, fixed; baked in as CAP.

  float* out       = (float*)d_out;
  float* moe       = out;                                  // [DSIZE*HIDDEN]
  float* scoreOut  = out + (size_t)DSIZE * HIDDEN;         // [T]
  float* assignOut = scoreOut + T_TOKENS;                  // [T] (int as float)
  float* slotsOut  = assignOut + T_TOKENS;                 // [T] (int as float)
  float* countsOut = slotsOut + T_TOKENS;                  // [E] (int as float)

  int*   expert = (int*)d_ws;                              // [T]
  int*   rank   = expert + T_TOKENS;                       // [T]
  float* score  = (float*)(rank + T_TOKENS);               // [T]
  int*   hist   = (int*)(score + T_TOKENS);                // [NGB*NEXP]
  int*   srcmap = hist + NGB * NEXP;                       // [DSIZE]
  float* sscore = (float*)(srcmap + DSIZE);                // [DSIZE]

  gate_kernel<<<NGB, BLK, 0, stream>>>(logits, expert, rank, score, hist,
                                       srcmap);
  finalize_kernel<<<NGB, BLK, 0, stream>>>(hist, expert, rank, score,
                                           srcmap, sscore,
                                           scoreOut, assignOut, slotsOut,
                                           countsOut);
  scatter_kernel<<<DSIZE / RPB, BLK, 0, stream>>>(act, srcmap, sscore, moe);
}